// Round 1
// baseline (2112.560 us; speedup 1.0000x reference)
//
#include <hip/hip_runtime.h>
#include <hip/hip_bf16.h>

// MapAgent: NatureCNN (3 convs + FC) -> map-write scan -> policy/value heads.
// T=32, B=64, TB=2048. All fp32.
//
// Structure notes:
//  * Convs: thread computes ALL (or half of) output channels for one spatial
//    position. Weight indices are wave-uniform -> s_load (scalar path), so the
//    VALU only does input loads + FMAs. Weights pre-transposed to [k][oc].
//  * conv1 weights pre-scaled by 1/255 (folds image preprocessing).
//  * Policy/value first layer: hidden@W1 computed via the scan recurrence
//    y_t = (1-d_t)*y_{t-1} + sum_c wfeat[t,c]*W1[c*256+off_t, :]
//    instead of materializing hidden [2048,8256] (saves 4.3 GF + 200 MB traffic).
//  * conv1->conv2 processed in chunks (2 or 4, chosen from ws_size) so the
//    conv1 activation buffer stays small. Peak ws: 101 MB (nc=2) / 75 MB (nc=4).

#define TT 32
#define BB 64
#define TBR 2048

// ---- workspace layout (float offsets) ----
#define OFF_W1T  0u           // 6144   : w1 transposed [192][32], pre-scaled /255
#define OFF_W2T  6144u        // 32768  : w2 transposed [512][64]
#define OFF_W3T  38912u       // 36864  : w3 transposed [576][64]
#define OFF_WF   75776u       // 65536  : wfeat [2048][32]
#define OFF_PF   141312u      // 131072 : posfeat [2048][64]
#define OFF_Y0   272384u      // 8192   : y0 [64][128]
#define OFF_YS   280576u      // 262144 : ystate [2048][128]
#define OFF_H    542720u      // 1048576: h [2048][512]
#define OFF_C2   1591296u     // 10616832 : conv2 out [2048][64][81]
#define OFF_C1   12208128u    // chunk conv1 out [CS][32][400]; reused for conv3 out [2048][3136]

// ---------------- weight prep: transpose to [k][oc] ----------------
__global__ __launch_bounds__(256) void prep_kernel(
    const float* __restrict__ w1, const float* __restrict__ w2,
    const float* __restrict__ w3, float* __restrict__ w1t,
    float* __restrict__ w2t, float* __restrict__ w3t) {
  int g = blockIdx.x * 256 + threadIdx.x;   // 75776 total
  if (g < 6144) {
    // conv1 k ordering = ky*24 + kx*3 + c ; w1 is [oc][c][ky*8+kx]
    int k = g >> 5, oc = g & 31;
    int c = k % 3, kyx = k / 3;             // kyx = ky*8+kx
    w1t[g] = w1[oc * 192 + c * 64 + kyx] * (1.0f / 255.0f);
    return;
  }
  int g2 = g - 6144;
  if (g2 < 32768) {                          // w2 [64][512] -> [512][64]
    int k = g2 >> 6, oc = g2 & 63;
    w2t[g2] = w2[oc * 512 + k];
    return;
  }
  int g3 = g2 - 32768;
  if (g3 < 36864) {                          // w3 [64][576] -> [576][64]
    int k = g3 >> 6, oc = g3 & 63;
    w3t[g3] = w3[oc * 576 + k];
  }
}

// ---------------- conv1: 84x84x3 -> [32][20][20], 8x8 stride 4 ----------------
__global__ __launch_bounds__(256) void conv1_kernel(
    const float* __restrict__ img, const float* __restrict__ w1t,
    const float* __restrict__ b1, float* __restrict__ out, int n0) {
  int gid = blockIdx.x * 256 + threadIdx.x;  // CS*400
  int li = gid / 400;
  int pos = gid - li * 400;
  int oy = pos / 20, ox = pos - (pos / 20) * 20;
  int n = n0 + li;
  float acc[32];
#pragma unroll
  for (int oc = 0; oc < 32; ++oc) acc[oc] = 0.f;
  const float* ib = img + (size_t)n * (84 * 84 * 3);
  for (int ky = 0; ky < 8; ++ky) {
    const float* row = ib + ((4 * oy + ky) * 84 + 4 * ox) * 3;
    const float* wk = w1t + ky * 24 * 32;
#pragma unroll
    for (int i = 0; i < 24; ++i) {           // kx*3 + c, contiguous in memory
      float v = row[i];
      const float* wr = wk + i * 32;         // wave-uniform -> s_load
#pragma unroll
      for (int oc = 0; oc < 32; ++oc) acc[oc] += v * wr[oc];
    }
  }
  float* ob = out + (size_t)li * (32 * 400) + pos;
#pragma unroll
  for (int oc = 0; oc < 32; ++oc) ob[oc * 400] = fmaxf(acc[oc] + b1[oc], 0.f);
}

// ---------------- conv2: [32][20][20] -> [64][9][9], 4x4 stride 2 ----------------
// oc split in halves of 32 for occupancy.
__global__ __launch_bounds__(256) void conv2_kernel(
    const float* __restrict__ in, const float* __restrict__ w2t,
    const float* __restrict__ b2, float* __restrict__ out, int n0) {
  int gid = blockIdx.x * 256 + threadIdx.x;  // CS*162
  int li = gid / 162;
  int rem = gid - li * 162;
  int half = rem / 81;
  int pos = rem - half * 81;
  int oy = pos / 9, ox = pos - (pos / 9) * 9;
  int oc0 = half * 32;
  float acc[32];
#pragma unroll
  for (int i = 0; i < 32; ++i) acc[i] = 0.f;
  const float* ib = in + (size_t)li * (32 * 400);
  for (int c = 0; c < 32; ++c) {
#pragma unroll
    for (int ky = 0; ky < 4; ++ky) {
      const float* row = ib + (c * 20 + 2 * oy + ky) * 20 + 2 * ox;
      const float* wk = w2t + (c * 16 + ky * 4) * 64 + oc0;
#pragma unroll
      for (int kx = 0; kx < 4; ++kx) {
        float v = row[kx];
        const float* wr = wk + kx * 64;
#pragma unroll
        for (int oc = 0; oc < 32; ++oc) acc[oc] += v * wr[oc];
      }
    }
  }
  int n = n0 + li;
  float* ob = out + (size_t)n * (64 * 81) + (size_t)oc0 * 81 + pos;
#pragma unroll
  for (int oc = 0; oc < 32; ++oc) ob[oc * 81] = fmaxf(acc[oc] + b2[oc0 + oc], 0.f);
}

// ---------------- conv3: [64][9][9] -> [64][7][7], 3x3 stride 1 ----------------
// Output stored as [n][3136] rows (c*49 + oy*7 + ox) = FC input layout.
__global__ __launch_bounds__(256) void conv3_kernel(
    const float* __restrict__ in, const float* __restrict__ w3t,
    const float* __restrict__ b3, float* __restrict__ out) {
  int gid = blockIdx.x * 256 + threadIdx.x;  // 2048*98
  int li = gid / 98;
  int rem = gid - li * 98;
  int half = rem / 49;
  int pos = rem - half * 49;
  int oy = pos / 7, ox = pos - (pos / 7) * 7;
  int oc0 = half * 32;
  float acc[32];
#pragma unroll
  for (int i = 0; i < 32; ++i) acc[i] = 0.f;
  const float* ib = in + (size_t)li * (64 * 81);
  for (int c = 0; c < 64; ++c) {
#pragma unroll
    for (int ky = 0; ky < 3; ++ky) {
      const float* row = ib + (c * 9 + oy + ky) * 9 + ox;
      const float* wk = w3t + ((c * 3 + ky) * 3) * 64 + oc0;
#pragma unroll
      for (int kx = 0; kx < 3; ++kx) {
        float v = row[kx];
        const float* wr = wk + kx * 64;
#pragma unroll
        for (int oc = 0; oc < 32; ++oc) acc[oc] += v * wr[oc];
      }
    }
  }
  float* ob = out + (size_t)li * 3136 + (size_t)oc0 * 49 + pos;
#pragma unroll
  for (int oc = 0; oc < 32; ++oc) ob[oc * 49] = fmaxf(acc[oc] + b3[oc0 + oc], 0.f);
}

// ---------------- FC: [2048,3136] @ [3136,512] + bias, ReLU ----------------
// LDS-tiled fp32 GEMM: BM=32, BN=64, BK=16, 256 threads, thread tile 2x4.
__global__ __launch_bounds__(256) void fc_gemm(
    const float* __restrict__ A, const float* __restrict__ Bw,
    const float* __restrict__ bias, float* __restrict__ C) {
  __shared__ float As[16][34];   // transposed, pad->8B align for float2 reads
  __shared__ float Bs[16][68];   // pad->16B align for float4 reads
  int tid = threadIdx.x;
  int m0 = blockIdx.y * 32, n0 = blockIdx.x * 64;
  int tx = tid & 15, ty = tid >> 4;
  int am = (tid * 2) >> 4;       // 0..31
  int ak = (tid * 2) & 15;       // even
  int bk = tid >> 6;             // 0..3
  int bn = tid & 63;
  float acc[2][4] = {{0.f, 0.f, 0.f, 0.f}, {0.f, 0.f, 0.f, 0.f}};
  for (int k0 = 0; k0 < 3136; k0 += 16) {
    float2 av = *(const float2*)(A + (size_t)(m0 + am) * 3136 + k0 + ak);
    float bv0 = Bw[(size_t)(k0 + bk) * 512 + n0 + bn];
    float bv1 = Bw[(size_t)(k0 + bk + 4) * 512 + n0 + bn];
    float bv2 = Bw[(size_t)(k0 + bk + 8) * 512 + n0 + bn];
    float bv3 = Bw[(size_t)(k0 + bk + 12) * 512 + n0 + bn];
    __syncthreads();
    As[ak][am] = av.x;
    As[ak + 1][am] = av.y;
    Bs[bk][bn] = bv0;
    Bs[bk + 4][bn] = bv1;
    Bs[bk + 8][bn] = bv2;
    Bs[bk + 12][bn] = bv3;
    __syncthreads();
#pragma unroll
    for (int kk = 0; kk < 16; ++kk) {
      float2 a = *(const float2*)&As[kk][ty * 2];
      float4 b = *(const float4*)&Bs[kk][tx * 4];
      acc[0][0] += a.x * b.x; acc[0][1] += a.x * b.y;
      acc[0][2] += a.x * b.z; acc[0][3] += a.x * b.w;
      acc[1][0] += a.y * b.x; acc[1][1] += a.y * b.y;
      acc[1][2] += a.y * b.z; acc[1][3] += a.y * b.w;
    }
  }
#pragma unroll
  for (int i = 0; i < 2; ++i) {
#pragma unroll
    for (int j = 0; j < 4; ++j) {
      int m = m0 + ty * 2 + i, n = n0 + tx * 4 + j;
      C[(size_t)m * 512 + n] = fmaxf(acc[i][j] + bias[n], 0.f);
    }
  }
}

// ---------------- wfeat = h @ Ww + bw : [2048,512]@[512,32] ----------------
__global__ __launch_bounds__(256) void wfeat_kernel(
    const float* __restrict__ h, const float* __restrict__ Ww,
    const float* __restrict__ bw, float* __restrict__ wf) {
  int g = blockIdx.x * 256 + threadIdx.x;   // 65536
  int row = g >> 5, oc = g & 31;
  float acc = bw[oc];
  const float* hr = h + (size_t)row * 512;
#pragma unroll 8
  for (int k = 0; k < 512; ++k) acc += hr[k] * Ww[k * 32 + oc];
  wf[g] = acc;
}

// ---------------- posfeat: one-hot MLP, one wave per row ----------------
__global__ __launch_bounds__(256) void posfeat_kernel(
    const int* __restrict__ pos, const float* __restrict__ wp1,
    const float* __restrict__ bp1, const float* __restrict__ wp2,
    const float* __restrict__ bp2, float* __restrict__ pf) {
  int row = (blockIdx.x * 256 + threadIdx.x) >> 6;  // 2048
  int l = threadIdx.x & 63;
  int p0 = pos[row * 2], p1 = pos[row * 2 + 1];
  float t1 = fmaxf(wp1[p0 * 64 + l] + wp1[(16 + p1) * 64 + l] + bp1[l], 0.f);
  float acc = bp2[l];
#pragma unroll
  for (int k = 0; k < 64; ++k) acc += __shfl(t1, k) * wp2[k * 64 + l];
  pf[row * 64 + l] = acc;
}

// ---------------- y0 = state0 @ [wpo1|wv1] : [64,8192]@[8192,128] ----------------
__global__ __launch_bounds__(256) void y0_kernel(
    const float* __restrict__ s0, const float* __restrict__ wpo1,
    const float* __restrict__ wv1, float* __restrict__ y0) {
  int g = blockIdx.x * 256 + threadIdx.x;   // 65536: (b, ks, n)
  int n = g & 127, ks = (g >> 7) & 7, b = g >> 10;
  const float* W = (n < 64) ? (wpo1 + n) : (wv1 + (n - 64));
  const float* s = s0 + (size_t)b * 8192 + ks * 1024;
  float acc = 0.f;
#pragma unroll 4
  for (int j = 0; j < 1024; ++j) acc += s[j] * W[(size_t)(ks * 1024 + j) * 64];
  atomicAdd(y0 + b * 128 + n, acc);
}

// ---------------- ystate: recurrence for hidden@W1 (cols 0..8191) ----------------
__global__ __launch_bounds__(128) void ystate_kernel(
    const float* __restrict__ y0, const float* __restrict__ done,
    const int* __restrict__ pos, const float* __restrict__ wf,
    const float* __restrict__ wpo1, const float* __restrict__ wv1,
    float* __restrict__ ys) {
  int b = blockIdx.x;
  int n = threadIdx.x;                      // 0..127
  const float* W = (n < 64) ? (wpo1 + n) : (wv1 + (n - 64));
  float y = y0[b * 128 + n];
  for (int t = 0; t < TT; ++t) {
    int row = t * BB + b;
    float mask = 1.f - done[row];
    int off = pos[row * 2] * 16 + pos[row * 2 + 1];
    y *= mask;
    const float* wfr = wf + row * 32;
#pragma unroll
    for (int c = 0; c < 32; ++c) y += wfr[c] * W[(size_t)(c * 256 + off) * 64];
    ys[(size_t)row * 128 + n] = y;
  }
}

// ---------------- final map state (output 2) ----------------
__global__ __launch_bounds__(256) void state_kernel(
    const float* __restrict__ s0, const float* __restrict__ done,
    const int* __restrict__ pos, const float* __restrict__ wf,
    float* __restrict__ out_state) {
  int b = blockIdx.x, tid = threadIdx.x;    // tid = spatial offset 0..255
  float s[32];
#pragma unroll
  for (int c = 0; c < 32; ++c) s[c] = s0[(size_t)b * 8192 + c * 256 + tid];
  for (int t = 0; t < TT; ++t) {
    int row = t * BB + b;
    float mask = 1.f - done[row];
    int off = pos[row * 2] * 16 + pos[row * 2 + 1];
#pragma unroll
    for (int c = 0; c < 32; ++c) s[c] *= mask;
    if (tid == off) {
#pragma unroll
      for (int c = 0; c < 32; ++c) s[c] += wf[row * 32 + c];
    }
  }
#pragma unroll
  for (int c = 0; c < 32; ++c) out_state[(size_t)b * 8192 + c * 256 + tid] = s[c];
}

// ---------------- heads: + pos-part of W1, ReLU, second layers ----------------
__global__ __launch_bounds__(256) void head_kernel(
    const float* __restrict__ ys, const float* __restrict__ pf,
    const float* __restrict__ wpo1, const float* __restrict__ wv1,
    const float* __restrict__ bpo1, const float* __restrict__ bv1,
    const float* __restrict__ wpo2, const float* __restrict__ bpo2,
    const float* __restrict__ wv2, const float* __restrict__ bv2,
    float* __restrict__ logits, float* __restrict__ vout) {
  int row = (blockIdx.x * 256 + threadIdx.x) >> 6;  // one wave per row
  int l = threadIdx.x & 63;
  float pfv = pf[row * 64 + l];
  float accp = bpo1[l] + ys[(size_t)row * 128 + l];
  float accv = bv1[l] + ys[(size_t)row * 128 + 64 + l];
#pragma unroll
  for (int k = 0; k < 64; ++k) {
    float pk = __shfl(pfv, k);
    accp += pk * wpo1[(size_t)(8192 + k) * 64 + l];
    accv += pk * wv1[(size_t)(8192 + k) * 64 + l];
  }
  float rp = fmaxf(accp, 0.f), rv = fmaxf(accv, 0.f);
#pragma unroll
  for (int a = 0; a < 5; ++a) {
    float pa = rp * wpo2[l * 5 + a];
#pragma unroll
    for (int m = 32; m >= 1; m >>= 1) pa += __shfl_xor(pa, m);
    if (l == 0) logits[row * 5 + a] = pa + bpo2[a];
  }
  float pv = rv * wv2[l];
#pragma unroll
  for (int m = 32; m >= 1; m >>= 1) pv += __shfl_xor(pv, m);
  if (l == 0) vout[row] = pv + bv2[0];
}

extern "C" void kernel_launch(void* const* d_in, const int* in_sizes, int n_in,
                              void* d_out, int out_size, void* d_ws, size_t ws_size,
                              hipStream_t stream) {
  const float* image = (const float*)d_in[0];
  const float* done = (const float*)d_in[1];
  const float* state0 = (const float*)d_in[2];
  const int* position = (const int*)d_in[3];
  const float* w1 = (const float*)d_in[4];
  const float* b1 = (const float*)d_in[5];
  const float* w2 = (const float*)d_in[6];
  const float* b2 = (const float*)d_in[7];
  const float* w3 = (const float*)d_in[8];
  const float* b3 = (const float*)d_in[9];
  const float* wfc = (const float*)d_in[10];
  const float* bfc = (const float*)d_in[11];
  const float* Ww = (const float*)d_in[12];
  const float* bw = (const float*)d_in[13];
  const float* wp1 = (const float*)d_in[14];
  const float* bp1 = (const float*)d_in[15];
  const float* wp2 = (const float*)d_in[16];
  const float* bp2 = (const float*)d_in[17];
  const float* wpo1 = (const float*)d_in[18];
  const float* bpo1 = (const float*)d_in[19];
  const float* wpo2 = (const float*)d_in[20];
  const float* bpo2 = (const float*)d_in[21];
  const float* wv1 = (const float*)d_in[22];
  const float* bv1 = (const float*)d_in[23];
  const float* wv2 = (const float*)d_in[24];
  const float* bv2 = (const float*)d_in[25];

  float* ws = (float*)d_ws;
  float* w1t = ws + OFF_W1T;
  float* w2t = ws + OFF_W2T;
  float* w3t = ws + OFF_W3T;
  float* wf = ws + OFF_WF;
  float* pfb = ws + OFF_PF;
  float* y0 = ws + OFF_Y0;
  float* ysb = ws + OFF_YS;
  float* h = ws + OFF_H;
  float* c2b = ws + OFF_C2;
  float* c1b = ws + OFF_C1;   // chunked conv1 out; later reused as conv3 out
  float* c3b = ws + OFF_C1;

  float* out = (float*)d_out;
  float* out_logits = out;            // [2048,5]
  float* out_v = out + 10240;         // [2048,1]
  float* out_state = out + 12288;     // [64,32,16,16]

  // chunk count for conv1->conv2: nc=2 needs 101.3 MB ws, nc=4 needs 75.1 MB
  int nc = (ws_size >= (size_t)25315328 * 4) ? 2 : 4;
  int cs = TBR / nc;                  // images per chunk

  hipMemsetAsync(y0, 0, 8192 * sizeof(float), stream);
  prep_kernel<<<296, 256, 0, stream>>>(w1, w2, w3, w1t, w2t, w3t);

  for (int c = 0; c < nc; ++c) {
    conv1_kernel<<<cs * 400 / 256, 256, 0, stream>>>(image, w1t, b1, c1b, c * cs);
    conv2_kernel<<<cs * 162 / 256, 256, 0, stream>>>(c1b, w2t, b2, c2b, c * cs);
  }
  conv3_kernel<<<784, 256, 0, stream>>>(c2b, w3t, b3, c3b);
  fc_gemm<<<dim3(8, 64), 256, 0, stream>>>(c3b, wfc, bfc, h);
  wfeat_kernel<<<256, 256, 0, stream>>>(h, Ww, bw, wf);
  posfeat_kernel<<<512, 256, 0, stream>>>(position, wp1, bp1, wp2, bp2, pfb);
  y0_kernel<<<256, 256, 0, stream>>>(state0, wpo1, wv1, y0);
  ystate_kernel<<<64, 128, 0, stream>>>(y0, done, position, wf, wpo1, wv1, ysb);
  state_kernel<<<64, 256, 0, stream>>>(state0, done, position, wf, out_state);
  head_kernel<<<512, 256, 0, stream>>>(ysb, pfb, wpo1, wv1, bpo1, bv1,
                                       wpo2, bpo2, wv2, bv2, out_logits, out_v);
}

// Round 2
// 1324.849 us; speedup vs baseline: 1.5946x; 1.5946x over previous
//
#include <hip/hip_runtime.h>
#include <hip/hip_bf16.h>

// MapAgent: NatureCNN (3 convs + FC) -> map-write scan -> policy/value heads.
// T=32, B=64, TB=2048. All fp32.
//
// R2 changes (theory: conv2/conv3 were latency-bound on per-lane divergent
// weight loads — half=rem/81 varies within the wave so weights couldn't use
// the scalar path; VALUBusy was 10%):
//  * conv2/conv3: one thread computes ALL 64 output channels for one spatial
//    position. Weight addresses now depend only on loop counters ->
//    wave-uniform -> s_load; VMEM instructions drop ~9x, ILP=64 per load.
//  * fc_gemm: 64x64 tile, 4x4 per-thread accumulators (halves LDS traffic
//    per FLOP vs 32x64/2x4).

#define TT 32
#define BB 64
#define TBR 2048

// ---- workspace layout (float offsets) ----
#define OFF_W1T  0u           // 6144   : w1 transposed [192][32], pre-scaled /255
#define OFF_W2T  6144u        // 32768  : w2 transposed [512][64]
#define OFF_W3T  38912u       // 36864  : w3 transposed [576][64]
#define OFF_WF   75776u       // 65536  : wfeat [2048][32]
#define OFF_PF   141312u      // 131072 : posfeat [2048][64]
#define OFF_Y0   272384u      // 8192   : y0 [64][128]
#define OFF_YS   280576u      // 262144 : ystate [2048][128]
#define OFF_H    542720u      // 1048576: h [2048][512]
#define OFF_C2   1591296u     // 10616832 : conv2 out [2048][64][81]
#define OFF_C1   12208128u    // chunk conv1 out [CS][32][400]; reused for conv3 out [2048][3136]

// ---------------- weight prep: transpose to [k][oc] ----------------
__global__ __launch_bounds__(256) void prep_kernel(
    const float* __restrict__ w1, const float* __restrict__ w2,
    const float* __restrict__ w3, float* __restrict__ w1t,
    float* __restrict__ w2t, float* __restrict__ w3t) {
  int g = blockIdx.x * 256 + threadIdx.x;   // 75776 total
  if (g < 6144) {
    // conv1 k ordering = ky*24 + kx*3 + c ; w1 is [oc][c][ky*8+kx]
    int k = g >> 5, oc = g & 31;
    int c = k % 3, kyx = k / 3;             // kyx = ky*8+kx
    w1t[g] = w1[oc * 192 + c * 64 + kyx] * (1.0f / 255.0f);
    return;
  }
  int g2 = g - 6144;
  if (g2 < 32768) {                          // w2 [64][512] -> [512][64]
    int k = g2 >> 6, oc = g2 & 63;
    w2t[g2] = w2[oc * 512 + k];
    return;
  }
  int g3 = g2 - 32768;
  if (g3 < 36864) {                          // w3 [64][576] -> [576][64]
    int k = g3 >> 6, oc = g3 & 63;
    w3t[g3] = w3[oc * 576 + k];
  }
}

// ---------------- conv1: 84x84x3 -> [32][20][20], 8x8 stride 4 ----------------
__global__ __launch_bounds__(256) void conv1_kernel(
    const float* __restrict__ img, const float* __restrict__ w1t,
    const float* __restrict__ b1, float* __restrict__ out, int n0) {
  int gid = blockIdx.x * 256 + threadIdx.x;  // CS*400
  int li = gid / 400;
  int pos = gid - li * 400;
  int oy = pos / 20, ox = pos - (pos / 20) * 20;
  int n = n0 + li;
  float acc[32];
#pragma unroll
  for (int oc = 0; oc < 32; ++oc) acc[oc] = 0.f;
  const float* ib = img + (size_t)n * (84 * 84 * 3);
  for (int ky = 0; ky < 8; ++ky) {
    const float* row = ib + ((4 * oy + ky) * 84 + 4 * ox) * 3;
    const float* wk = w1t + ky * 24 * 32;
#pragma unroll
    for (int i = 0; i < 24; ++i) {           // kx*3 + c, contiguous in memory
      float v = row[i];
      const float* wr = wk + i * 32;         // wave-uniform -> s_load
#pragma unroll
      for (int oc = 0; oc < 32; ++oc) acc[oc] += v * wr[oc];
    }
  }
  float* ob = out + (size_t)li * (32 * 400) + pos;
#pragma unroll
  for (int oc = 0; oc < 32; ++oc) ob[oc * 400] = fmaxf(acc[oc] + b1[oc], 0.f);
}

// ---------------- conv2: [32][20][20] -> [64][9][9], 4x4 stride 2 ----------------
// One thread = one spatial position, ALL 64 output channels (uniform weights).
__global__ __launch_bounds__(256) void conv2_kernel(
    const float* __restrict__ in, const float* __restrict__ w2t,
    const float* __restrict__ b2, float* __restrict__ out, int n0) {
  int gid = blockIdx.x * 256 + threadIdx.x;  // CS*81
  int li = gid / 81;
  int pos = gid - li * 81;
  int oy = pos / 9, ox = pos - (pos / 9) * 9;
  float acc[64];
#pragma unroll
  for (int i = 0; i < 64; ++i) acc[i] = 0.f;
  const float* ib = in + (size_t)li * (32 * 400);
  for (int c = 0; c < 32; ++c) {
#pragma unroll
    for (int ky = 0; ky < 4; ++ky) {
      const float* row = ib + (c * 20 + 2 * oy + ky) * 20 + 2 * ox;
      const float* wk = w2t + (c * 16 + ky * 4) * 64;
#pragma unroll
      for (int kx = 0; kx < 4; ++kx) {
        float v = row[kx];
        const float* wr = wk + kx * 64;      // wave-uniform -> s_load
#pragma unroll
        for (int oc = 0; oc < 64; ++oc) acc[oc] += v * wr[oc];
      }
    }
  }
  int n = n0 + li;
  float* ob = out + (size_t)n * (64 * 81) + pos;
#pragma unroll
  for (int oc = 0; oc < 64; ++oc) ob[oc * 81] = fmaxf(acc[oc] + b2[oc], 0.f);
}

// ---------------- conv3: [64][9][9] -> [64][7][7], 3x3 stride 1 ----------------
// One thread = one spatial position, ALL 64 output channels (uniform weights).
// Output stored as [n][3136] rows (c*49 + oy*7 + ox) = FC input layout.
__global__ __launch_bounds__(256) void conv3_kernel(
    const float* __restrict__ in, const float* __restrict__ w3t,
    const float* __restrict__ b3, float* __restrict__ out) {
  int gid = blockIdx.x * 256 + threadIdx.x;  // 2048*49
  int li = gid / 49;
  int pos = gid - li * 49;
  int oy = pos / 7, ox = pos - (pos / 7) * 7;
  float acc[64];
#pragma unroll
  for (int i = 0; i < 64; ++i) acc[i] = 0.f;
  const float* ib = in + (size_t)li * (64 * 81);
  for (int c = 0; c < 64; ++c) {
#pragma unroll
    for (int ky = 0; ky < 3; ++ky) {
      const float* row = ib + (c * 9 + oy + ky) * 9 + ox;
      const float* wk = w3t + ((c * 3 + ky) * 3) * 64;
#pragma unroll
      for (int kx = 0; kx < 3; ++kx) {
        float v = row[kx];
        const float* wr = wk + kx * 64;      // wave-uniform -> s_load
#pragma unroll
        for (int oc = 0; oc < 64; ++oc) acc[oc] += v * wr[oc];
      }
    }
  }
  float* ob = out + (size_t)li * 3136 + pos;
#pragma unroll
  for (int oc = 0; oc < 64; ++oc) ob[oc * 49] = fmaxf(acc[oc] + b3[oc], 0.f);
}

// ---------------- FC: [2048,3136] @ [3136,512] + bias, ReLU ----------------
// LDS-tiled fp32 GEMM: BM=64, BN=64, BK=16, 256 threads, thread tile 4x4.
__global__ __launch_bounds__(256) void fc_gemm(
    const float* __restrict__ A, const float* __restrict__ Bw,
    const float* __restrict__ bias, float* __restrict__ C) {
  __shared__ float As[16][68];   // [k][m], row stride 272B (16-mult) for float4
  __shared__ float Bs[16][68];   // [k][n]
  int tid = threadIdx.x;
  int m0 = blockIdx.y * 64, n0 = blockIdx.x * 64;
  int tx = tid & 15, ty = tid >> 4;
  int aRow = tid & 63;           // m within tile
  int aK = (tid >> 6) * 4;       // k0 offset 0/4/8/12 (wave-uniform)
  int bN = tid & 63;
  int bK = tid >> 6;             // 0..3 (wave-uniform)
  float acc[4][4];
#pragma unroll
  for (int i = 0; i < 4; ++i)
#pragma unroll
    for (int j = 0; j < 4; ++j) acc[i][j] = 0.f;
  const float* aBase = A + (size_t)(m0 + aRow) * 3136;
  for (int k0 = 0; k0 < 3136; k0 += 16) {
    float4 av = *(const float4*)(aBase + k0 + aK);
    float bv[4];
#pragma unroll
    for (int j = 0; j < 4; ++j)
      bv[j] = Bw[(size_t)(k0 + bK + 4 * j) * 512 + n0 + bN];
    __syncthreads();
#pragma unroll
    for (int j = 0; j < 4; ++j) Bs[bK + 4 * j][bN] = bv[j];
    As[aK][aRow] = av.x;
    As[aK + 1][aRow] = av.y;
    As[aK + 2][aRow] = av.z;
    As[aK + 3][aRow] = av.w;
    __syncthreads();
#pragma unroll
    for (int kk = 0; kk < 16; ++kk) {
      float4 a = *(const float4*)&As[kk][ty * 4];
      float4 b = *(const float4*)&Bs[kk][tx * 4];
      float af[4] = {a.x, a.y, a.z, a.w};
      float bf[4] = {b.x, b.y, b.z, b.w};
#pragma unroll
      for (int i = 0; i < 4; ++i)
#pragma unroll
        for (int j = 0; j < 4; ++j) acc[i][j] += af[i] * bf[j];
    }
  }
#pragma unroll
  for (int i = 0; i < 4; ++i) {
#pragma unroll
    for (int j = 0; j < 4; ++j) {
      int m = m0 + ty * 4 + i, n = n0 + tx * 4 + j;
      C[(size_t)m * 512 + n] = fmaxf(acc[i][j] + bias[n], 0.f);
    }
  }
}

// ---------------- wfeat = h @ Ww + bw : [2048,512]@[512,32] ----------------
__global__ __launch_bounds__(256) void wfeat_kernel(
    const float* __restrict__ h, const float* __restrict__ Ww,
    const float* __restrict__ bw, float* __restrict__ wf) {
  int g = blockIdx.x * 256 + threadIdx.x;   // 65536
  int row = g >> 5, oc = g & 31;
  float acc = bw[oc];
  const float* hr = h + (size_t)row * 512;
#pragma unroll 8
  for (int k = 0; k < 512; ++k) acc += hr[k] * Ww[k * 32 + oc];
  wf[g] = acc;
}

// ---------------- posfeat: one-hot MLP, one wave per row ----------------
__global__ __launch_bounds__(256) void posfeat_kernel(
    const int* __restrict__ pos, const float* __restrict__ wp1,
    const float* __restrict__ bp1, const float* __restrict__ wp2,
    const float* __restrict__ bp2, float* __restrict__ pf) {
  int row = (blockIdx.x * 256 + threadIdx.x) >> 6;  // 2048
  int l = threadIdx.x & 63;
  int p0 = pos[row * 2], p1 = pos[row * 2 + 1];
  float t1 = fmaxf(wp1[p0 * 64 + l] + wp1[(16 + p1) * 64 + l] + bp1[l], 0.f);
  float acc = bp2[l];
#pragma unroll
  for (int k = 0; k < 64; ++k) acc += __shfl(t1, k) * wp2[k * 64 + l];
  pf[row * 64 + l] = acc;
}

// ---------------- y0 = state0 @ [wpo1|wv1] : [64,8192]@[8192,128] ----------------
__global__ __launch_bounds__(256) void y0_kernel(
    const float* __restrict__ s0, const float* __restrict__ wpo1,
    const float* __restrict__ wv1, float* __restrict__ y0) {
  int g = blockIdx.x * 256 + threadIdx.x;   // 65536: (b, ks, n)
  int n = g & 127, ks = (g >> 7) & 7, b = g >> 10;
  const float* W = (n < 64) ? (wpo1 + n) : (wv1 + (n - 64));
  const float* s = s0 + (size_t)b * 8192 + ks * 1024;
  float acc = 0.f;
#pragma unroll 4
  for (int j = 0; j < 1024; ++j) acc += s[j] * W[(size_t)(ks * 1024 + j) * 64];
  atomicAdd(y0 + b * 128 + n, acc);
}

// ---------------- ystate: recurrence for hidden@W1 (cols 0..8191) ----------------
__global__ __launch_bounds__(128) void ystate_kernel(
    const float* __restrict__ y0, const float* __restrict__ done,
    const int* __restrict__ pos, const float* __restrict__ wf,
    const float* __restrict__ wpo1, const float* __restrict__ wv1,
    float* __restrict__ ys) {
  int b = blockIdx.x;
  int n = threadIdx.x;                      // 0..127
  const float* W = (n < 64) ? (wpo1 + n) : (wv1 + (n - 64));
  float y = y0[b * 128 + n];
  for (int t = 0; t < TT; ++t) {
    int row = t * BB + b;
    float mask = 1.f - done[row];
    int off = pos[row * 2] * 16 + pos[row * 2 + 1];
    y *= mask;
    const float* wfr = wf + row * 32;
#pragma unroll
    for (int c = 0; c < 32; ++c) y += wfr[c] * W[(size_t)(c * 256 + off) * 64];
    ys[(size_t)row * 128 + n] = y;
  }
}

// ---------------- final map state (output 2) ----------------
__global__ __launch_bounds__(256) void state_kernel(
    const float* __restrict__ s0, const float* __restrict__ done,
    const int* __restrict__ pos, const float* __restrict__ wf,
    float* __restrict__ out_state) {
  int b = blockIdx.x, tid = threadIdx.x;    // tid = spatial offset 0..255
  float s[32];
#pragma unroll
  for (int c = 0; c < 32; ++c) s[c] = s0[(size_t)b * 8192 + c * 256 + tid];
  for (int t = 0; t < TT; ++t) {
    int row = t * BB + b;
    float mask = 1.f - done[row];
    int off = pos[row * 2] * 16 + pos[row * 2 + 1];
#pragma unroll
    for (int c = 0; c < 32; ++c) s[c] *= mask;
    if (tid == off) {
#pragma unroll
      for (int c = 0; c < 32; ++c) s[c] += wf[row * 32 + c];
    }
  }
#pragma unroll
  for (int c = 0; c < 32; ++c) out_state[(size_t)b * 8192 + c * 256 + tid] = s[c];
}

// ---------------- heads: + pos-part of W1, ReLU, second layers ----------------
__global__ __launch_bounds__(256) void head_kernel(
    const float* __restrict__ ys, const float* __restrict__ pf,
    const float* __restrict__ wpo1, const float* __restrict__ wv1,
    const float* __restrict__ bpo1, const float* __restrict__ bv1,
    const float* __restrict__ wpo2, const float* __restrict__ bpo2,
    const float* __restrict__ wv2, const float* __restrict__ bv2,
    float* __restrict__ logits, float* __restrict__ vout) {
  int row = (blockIdx.x * 256 + threadIdx.x) >> 6;  // one wave per row
  int l = threadIdx.x & 63;
  float pfv = pf[row * 64 + l];
  float accp = bpo1[l] + ys[(size_t)row * 128 + l];
  float accv = bv1[l] + ys[(size_t)row * 128 + 64 + l];
#pragma unroll
  for (int k = 0; k < 64; ++k) {
    float pk = __shfl(pfv, k);
    accp += pk * wpo1[(size_t)(8192 + k) * 64 + l];
    accv += pk * wv1[(size_t)(8192 + k) * 64 + l];
  }
  float rp = fmaxf(accp, 0.f), rv = fmaxf(accv, 0.f);
#pragma unroll
  for (int a = 0; a < 5; ++a) {
    float pa = rp * wpo2[l * 5 + a];
#pragma unroll
    for (int m = 32; m >= 1; m >>= 1) pa += __shfl_xor(pa, m);
    if (l == 0) logits[row * 5 + a] = pa + bpo2[a];
  }
  float pv = rv * wv2[l];
#pragma unroll
  for (int m = 32; m >= 1; m >>= 1) pv += __shfl_xor(pv, m);
  if (l == 0) vout[row] = pv + bv2[0];
}

extern "C" void kernel_launch(void* const* d_in, const int* in_sizes, int n_in,
                              void* d_out, int out_size, void* d_ws, size_t ws_size,
                              hipStream_t stream) {
  const float* image = (const float*)d_in[0];
  const float* done = (const float*)d_in[1];
  const float* state0 = (const float*)d_in[2];
  const int* position = (const int*)d_in[3];
  const float* w1 = (const float*)d_in[4];
  const float* b1 = (const float*)d_in[5];
  const float* w2 = (const float*)d_in[6];
  const float* b2 = (const float*)d_in[7];
  const float* w3 = (const float*)d_in[8];
  const float* b3 = (const float*)d_in[9];
  const float* wfc = (const float*)d_in[10];
  const float* bfc = (const float*)d_in[11];
  const float* Ww = (const float*)d_in[12];
  const float* bw = (const float*)d_in[13];
  const float* wp1 = (const float*)d_in[14];
  const float* bp1 = (const float*)d_in[15];
  const float* wp2 = (const float*)d_in[16];
  const float* bp2 = (const float*)d_in[17];
  const float* wpo1 = (const float*)d_in[18];
  const float* bpo1 = (const float*)d_in[19];
  const float* wpo2 = (const float*)d_in[20];
  const float* bpo2 = (const float*)d_in[21];
  const float* wv1 = (const float*)d_in[22];
  const float* bv1 = (const float*)d_in[23];
  const float* wv2 = (const float*)d_in[24];
  const float* bv2 = (const float*)d_in[25];

  float* ws = (float*)d_ws;
  float* w1t = ws + OFF_W1T;
  float* w2t = ws + OFF_W2T;
  float* w3t = ws + OFF_W3T;
  float* wf = ws + OFF_WF;
  float* pfb = ws + OFF_PF;
  float* y0 = ws + OFF_Y0;
  float* ysb = ws + OFF_YS;
  float* h = ws + OFF_H;
  float* c2b = ws + OFF_C2;
  float* c1b = ws + OFF_C1;   // chunked conv1 out; later reused as conv3 out
  float* c3b = ws + OFF_C1;

  float* out = (float*)d_out;
  float* out_logits = out;            // [2048,5]
  float* out_v = out + 10240;         // [2048,1]
  float* out_state = out + 12288;     // [64,32,16,16]

  // chunk count for conv1->conv2: nc=2 needs 101.3 MB ws, nc=4 needs 75.1 MB
  int nc = (ws_size >= (size_t)25315328 * 4) ? 2 : 4;
  int cs = TBR / nc;                  // images per chunk

  hipMemsetAsync(y0, 0, 8192 * sizeof(float), stream);
  prep_kernel<<<296, 256, 0, stream>>>(w1, w2, w3, w1t, w2t, w3t);

  for (int c = 0; c < nc; ++c) {
    conv1_kernel<<<cs * 400 / 256, 256, 0, stream>>>(image, w1t, b1, c1b, c * cs);
    conv2_kernel<<<(cs * 81 + 255) / 256, 256, 0, stream>>>(c1b, w2t, b2, c2b, c * cs);
  }
  conv3_kernel<<<392, 256, 0, stream>>>(c2b, w3t, b3, c3b);
  fc_gemm<<<dim3(8, 32), 256, 0, stream>>>(c3b, wfc, bfc, h);
  wfeat_kernel<<<256, 256, 0, stream>>>(h, Ww, bw, wf);
  posfeat_kernel<<<512, 256, 0, stream>>>(position, wp1, bp1, wp2, bp2, pfb);
  y0_kernel<<<256, 256, 0, stream>>>(state0, wpo1, wv1, y0);
  ystate_kernel<<<64, 128, 0, stream>>>(y0, done, position, wf, wpo1, wv1, ysb);
  state_kernel<<<64, 256, 0, stream>>>(state0, done, position, wf, out_state);
  head_kernel<<<512, 256, 0, stream>>>(ysb, pfb, wpo1, wv1, bpo1, bv1,
                                       wpo2, bpo2, wv2, bv2, out_logits, out_v);
}